// Round 1
// baseline (1343.344 us; speedup 1.0000x reference)
//
#include <hip/hip_runtime.h>
#include <hip/hip_bf16.h>

#define N_NODES 100000
#define N_EDGES 600000
#define D_IN 128
#define D_OUT 512

typedef __bf16 bf16x8 __attribute__((ext_vector_type(8)));
typedef float f32x4 __attribute__((ext_vector_type(4)));

// ---------------- kernel 1: h = x (residual folded into accumulator) --------
__global__ void k_init(const float* __restrict__ x, float* __restrict__ h) {
    int i = blockIdx.x * blockDim.x + threadIdx.x;  // float4 index
    if (i < (N_NODES * D_IN / 4)) {
        ((float4*)h)[i] = ((const float4*)x)[i];
    }
}

// ---------------- kernel 2: h[row[e]] += x[col[e]] --------------------------
// 32 threads per edge, float4 per thread (128 floats = D_IN).
__global__ void k_scatter(const float* __restrict__ x, const int* __restrict__ ei,
                          float* __restrict__ h) {
    unsigned t = blockIdx.x * blockDim.x + threadIdx.x;
    unsigned e = t >> 5;
    if (e >= N_EDGES) return;
    int j = t & 31;
    int r = ei[e];            // destination row
    int c = ei[N_EDGES + e];  // source col
    float4 v = ((const float4*)(x + (size_t)c * D_IN))[j];
    float* dst = h + (size_t)r * D_IN + (j << 2);
    unsafeAtomicAdd(dst + 0, v.x);
    unsafeAtomicAdd(dst + 1, v.y);
    unsafeAtomicAdd(dst + 2, v.z);
    unsafeAtomicAdd(dst + 3, v.w);
}

// ---------------- kernel 3: out = h @ W^T + b (bf16 MFMA) -------------------
// M=100000, N=512, K=128. Block tile 128x64, full K in LDS (no K loop).
// 4 waves: wave tile 64x32 = 4x2 MFMA tiles of 16x16, 4 K-steps of 32.
#define BM 128
#define BN 64
#define LDA 136   // 128 + 8 pad: row stride 272B -> 2-way bank alias (free)
#define LDB 136

__device__ inline bf16x8 cvt8(float4 v0, float4 v1) {
    bf16x8 u = { (__bf16)v0.x, (__bf16)v0.y, (__bf16)v0.z, (__bf16)v0.w,
                 (__bf16)v1.x, (__bf16)v1.y, (__bf16)v1.z, (__bf16)v1.w };
    return u;
}

__launch_bounds__(256, 2)
__global__ void k_gemm(const float* __restrict__ h, const float* __restrict__ W,
                       const float* __restrict__ bias, float* __restrict__ out) {
    __shared__ __bf16 As[BM * LDA];  // 128 x 136 bf16 = 34816 B
    __shared__ __bf16 Bs[BN * LDB];  //  64 x 136 bf16 = 17408 B

    int tid = threadIdx.x;
    int m0 = blockIdx.y * BM;
    int n0 = blockIdx.x * BN;

    // ---- stage A: h[m0 .. m0+127][0..127] -> bf16 LDS (8 elems/thread/iter)
    #pragma unroll
    for (int it = 0; it < 8; ++it) {
        int i = tid + it * 256;           // chunk index, 8 elems per chunk
        int r = i >> 4;                   // 16 chunks per row
        int c = (i & 15) << 3;
        int gr = m0 + r;
        if (gr > N_NODES - 1) gr = N_NODES - 1;   // clamp tail (stores guarded)
        const float* src = h + (size_t)gr * D_IN + c;
        float4 v0 = *(const float4*)(src);
        float4 v1 = *(const float4*)(src + 4);
        *(bf16x8*)&As[r * LDA + c] = cvt8(v0, v1);
    }
    // ---- stage B: W[n0 .. n0+63][0..127] -> bf16 LDS
    #pragma unroll
    for (int it = 0; it < 4; ++it) {
        int i = tid + it * 256;
        int r = i >> 4;
        int c = (i & 15) << 3;
        const float* src = W + (size_t)(n0 + r) * D_IN + c;
        float4 v0 = *(const float4*)(src);
        float4 v1 = *(const float4*)(src + 4);
        *(bf16x8*)&Bs[r * LDB + c] = cvt8(v0, v1);
    }
    __syncthreads();

    int lane = tid & 63;
    int wave = tid >> 6;
    int wm = wave & 1;    // m-half (0..1) -> 64 rows
    int wn = wave >> 1;   // n-half (0..1) -> 32 cols
    int quad = lane >> 4;
    int l16 = lane & 15;

    f32x4 acc[4][2] = {};

    const __bf16* Abase = &As[(wm * 64 + l16) * LDA + quad * 8];
    const __bf16* Bbase = &Bs[(wn * 32 + l16) * LDB + quad * 8];

    #pragma unroll
    for (int ks = 0; ks < 4; ++ks) {
        bf16x8 a0 = *(const bf16x8*)(Abase + ks * 32);
        bf16x8 a1 = *(const bf16x8*)(Abase + 16 * LDA + ks * 32);
        bf16x8 a2 = *(const bf16x8*)(Abase + 32 * LDA + ks * 32);
        bf16x8 a3 = *(const bf16x8*)(Abase + 48 * LDA + ks * 32);
        bf16x8 b0 = *(const bf16x8*)(Bbase + ks * 32);
        bf16x8 b1 = *(const bf16x8*)(Bbase + 16 * LDB + ks * 32);
        acc[0][0] = __builtin_amdgcn_mfma_f32_16x16x32_bf16(a0, b0, acc[0][0], 0, 0, 0);
        acc[0][1] = __builtin_amdgcn_mfma_f32_16x16x32_bf16(a0, b1, acc[0][1], 0, 0, 0);
        acc[1][0] = __builtin_amdgcn_mfma_f32_16x16x32_bf16(a1, b0, acc[1][0], 0, 0, 0);
        acc[1][1] = __builtin_amdgcn_mfma_f32_16x16x32_bf16(a1, b1, acc[1][1], 0, 0, 0);
        acc[2][0] = __builtin_amdgcn_mfma_f32_16x16x32_bf16(a2, b0, acc[2][0], 0, 0, 0);
        acc[2][1] = __builtin_amdgcn_mfma_f32_16x16x32_bf16(a2, b1, acc[2][1], 0, 0, 0);
        acc[3][0] = __builtin_amdgcn_mfma_f32_16x16x32_bf16(a3, b0, acc[3][0], 0, 0, 0);
        acc[3][1] = __builtin_amdgcn_mfma_f32_16x16x32_bf16(a3, b1, acc[3][1], 0, 0, 0);
    }

    // ---- epilogue: C layout col=lane&15, row=quad*4+reg; add bias, guard M
    float bias0 = bias[n0 + wn * 32 + l16];
    float bias1 = bias[n0 + wn * 32 + 16 + l16];
    #pragma unroll
    for (int mt = 0; mt < 4; ++mt) {
        int mrow = m0 + wm * 64 + mt * 16 + quad * 4;
        #pragma unroll
        for (int nt = 0; nt < 2; ++nt) {
            int ncol = n0 + wn * 32 + nt * 16 + l16;
            float bv = nt ? bias1 : bias0;
            #pragma unroll
            for (int rg = 0; rg < 4; ++rg) {
                int m = mrow + rg;
                if (m < N_NODES)
                    out[(size_t)m * D_OUT + ncol] = acc[mt][nt][rg] + bv;
            }
        }
    }
}

extern "C" void kernel_launch(void* const* d_in, const int* in_sizes, int n_in,
                              void* d_out, int out_size, void* d_ws, size_t ws_size,
                              hipStream_t stream) {
    const float* x  = (const float*)d_in[0];
    const int*   ei = (const int*)d_in[1];
    const float* W  = (const float*)d_in[2];
    const float* b  = (const float*)d_in[3];
    float* out = (float*)d_out;
    float* h   = (float*)d_ws;   // N_NODES * D_IN fp32 = 51.2 MB

    // 1) h = x
    k_init<<<(N_NODES * D_IN / 4 + 255) / 256, 256, 0, stream>>>(x, h);
    // 2) h[row] += x[col]
    k_scatter<<<(N_EDGES * 32) / 256, 256, 0, stream>>>(x, ei, h);
    // 3) out = h @ W^T + b
    k_gemm<<<dim3(D_OUT / BN, (N_NODES + BM - 1) / BM), 256, 0, stream>>>(h, W, b, out);
}

// Round 2
// 389.712 us; speedup vs baseline: 3.4470x; 3.4470x over previous
//
#include <hip/hip_runtime.h>
#include <hip/hip_bf16.h>

#define N_NODES 100000
#define N_EDGES 600000
#define D_IN 128
#define D_OUT 512
#define CAP 40        // bucket capacity per node (Poisson(6): P(deg>=40) ~ 1e-20)
#define OVF_CAP 1024

typedef __bf16 bf16x8 __attribute__((ext_vector_type(8)));
typedef __bf16 bf16x2 __attribute__((ext_vector_type(2)));
typedef float f32x4 __attribute__((ext_vector_type(4)));

// ---- workspace layout (bytes) ----
// h_bf16 : [0, 25,600,000)                N_NODES*128*2
// cnt    : [25,600,000, 26,000,000)       N_NODES*4
// ovf_cnt: [26,000,000, 26,000,016)       (memset covers cnt+ovf_cnt in one go)
// ovf    : [26,000,016, 26,008,208)       OVF_CAP * int2
// bucket : [26,008,208, 42,008,208)       N_NODES*CAP*4
#define OFF_CNT   25600000
#define OFF_OVFC  26000000
#define OFF_OVF   26000016
#define OFF_BUCK  26008208

// ---------------- kernel 1: build per-node buckets --------------------------
__global__ void k_bucket(const int* __restrict__ ei, int* __restrict__ cnt,
                         int* __restrict__ bucket, int* __restrict__ ovf_cnt,
                         int2* __restrict__ ovf) {
    int e = blockIdx.x * blockDim.x + threadIdx.x;
    if (e >= N_EDGES) return;
    int r = ei[e];            // destination
    int c = ei[N_EDGES + e];  // source
    int slot = atomicAdd(&cnt[r], 1);
    if (slot < CAP) {
        bucket[(size_t)r * CAP + slot] = c;
    } else {
        int oi = atomicAdd(ovf_cnt, 1);
        if (oi < OVF_CAP) ovf[oi] = make_int2(r, c);
    }
}

// ---------------- kernel 2: h[r] = bf16( x[r] + sum_{c in bucket[r]} x[c] ) -
// one wave per node; lane holds float2 (64 lanes * 2 = 128 floats)
__global__ void k_agg(const float* __restrict__ x, const int* __restrict__ cnt,
                      const int* __restrict__ bucket, const int* __restrict__ ovf_cnt,
                      const int2* __restrict__ ovf, __bf16* __restrict__ h) {
    int gw = (blockIdx.x * blockDim.x + threadIdx.x) >> 6;  // wave id = node
    if (gw >= N_NODES) return;
    int lane = threadIdx.x & 63;
    const float2* xr = (const float2*)x;

    float2 acc = xr[(size_t)gw * 64 + lane];  // residual x[gw]
    float ax2 = 0.f, ay2 = 0.f;

    int deg = __builtin_amdgcn_readfirstlane(cnt[gw]);
    int dmin = deg < CAP ? deg : CAP;
    const int* bk = bucket + (size_t)gw * CAP;

    int d = 0;
    for (; d + 1 < dmin; d += 2) {
        int c0 = __builtin_amdgcn_readfirstlane(bk[d]);
        int c1 = __builtin_amdgcn_readfirstlane(bk[d + 1]);
        float2 v0 = xr[(size_t)c0 * 64 + lane];
        float2 v1 = xr[(size_t)c1 * 64 + lane];
        acc.x += v0.x; acc.y += v0.y;
        ax2 += v1.x;   ay2 += v1.y;
    }
    if (d < dmin) {
        int c0 = __builtin_amdgcn_readfirstlane(bk[d]);
        float2 v0 = xr[(size_t)c0 * 64 + lane];
        acc.x += v0.x; acc.y += v0.y;
    }
    acc.x += ax2; acc.y += ay2;

    if (deg > CAP) {  // statistically never; correctness fallback
        int n = *ovf_cnt;
        if (n > OVF_CAP) n = OVF_CAP;
        for (int i = 0; i < n; ++i) {
            int2 e = ovf[i];
            if (e.x == gw) {
                float2 v = xr[(size_t)e.y * 64 + lane];
                acc.x += v.x; acc.y += v.y;
            }
        }
    }

    bf16x2 o = { (__bf16)acc.x, (__bf16)acc.y };
    ((bf16x2*)h)[(size_t)gw * 64 + lane] = o;
}

// ---------------- kernel 3: out = h @ W^T + b (bf16 MFMA) -------------------
#define BM 128
#define BN 64
#define LDA 136   // +8 pad: row stride 272B -> 2-way bank alias (free per m136)
#define LDB 136

__device__ inline bf16x8 cvt8(float4 v0, float4 v1) {
    bf16x8 u = { (__bf16)v0.x, (__bf16)v0.y, (__bf16)v0.z, (__bf16)v0.w,
                 (__bf16)v1.x, (__bf16)v1.y, (__bf16)v1.z, (__bf16)v1.w };
    return u;
}

__launch_bounds__(256, 2)
__global__ void k_gemm(const __bf16* __restrict__ h, const float* __restrict__ W,
                       const float* __restrict__ bias, float* __restrict__ out) {
    __shared__ __bf16 As[BM * LDA];
    __shared__ __bf16 Bs[BN * LDB];

    int tid = threadIdx.x;
    int m0 = blockIdx.y * BM;
    int n0 = blockIdx.x * BN;

    // stage A: 128x128 bf16, 16B loads
    #pragma unroll
    for (int it = 0; it < 8; ++it) {
        int i = tid + it * 256;
        int r = i >> 4;
        int c = (i & 15) << 3;
        int gr = m0 + r;
        if (gr > N_NODES - 1) gr = N_NODES - 1;
        *(bf16x8*)&As[r * LDA + c] = *(const bf16x8*)(h + (size_t)gr * D_IN + c);
    }
    // stage B: W fp32 -> bf16
    #pragma unroll
    for (int it = 0; it < 4; ++it) {
        int i = tid + it * 256;
        int r = i >> 4;
        int c = (i & 15) << 3;
        const float* src = W + (size_t)(n0 + r) * D_IN + c;
        float4 v0 = *(const float4*)(src);
        float4 v1 = *(const float4*)(src + 4);
        *(bf16x8*)&Bs[r * LDB + c] = cvt8(v0, v1);
    }
    __syncthreads();

    int lane = tid & 63;
    int wave = tid >> 6;
    int wm = wave & 1;
    int wn = wave >> 1;
    int quad = lane >> 4;
    int l16 = lane & 15;

    f32x4 acc[4][2] = {};

    const __bf16* Abase = &As[(wm * 64 + l16) * LDA + quad * 8];
    const __bf16* Bbase = &Bs[(wn * 32 + l16) * LDB + quad * 8];

    #pragma unroll
    for (int ks = 0; ks < 4; ++ks) {
        bf16x8 a0 = *(const bf16x8*)(Abase + ks * 32);
        bf16x8 a1 = *(const bf16x8*)(Abase + 16 * LDA + ks * 32);
        bf16x8 a2 = *(const bf16x8*)(Abase + 32 * LDA + ks * 32);
        bf16x8 a3 = *(const bf16x8*)(Abase + 48 * LDA + ks * 32);
        bf16x8 b0 = *(const bf16x8*)(Bbase + ks * 32);
        bf16x8 b1 = *(const bf16x8*)(Bbase + 16 * LDB + ks * 32);
        acc[0][0] = __builtin_amdgcn_mfma_f32_16x16x32_bf16(a0, b0, acc[0][0], 0, 0, 0);
        acc[0][1] = __builtin_amdgcn_mfma_f32_16x16x32_bf16(a0, b1, acc[0][1], 0, 0, 0);
        acc[1][0] = __builtin_amdgcn_mfma_f32_16x16x32_bf16(a1, b0, acc[1][0], 0, 0, 0);
        acc[1][1] = __builtin_amdgcn_mfma_f32_16x16x32_bf16(a1, b1, acc[1][1], 0, 0, 0);
        acc[2][0] = __builtin_amdgcn_mfma_f32_16x16x32_bf16(a2, b0, acc[2][0], 0, 0, 0);
        acc[2][1] = __builtin_amdgcn_mfma_f32_16x16x32_bf16(a2, b1, acc[2][1], 0, 0, 0);
        acc[3][0] = __builtin_amdgcn_mfma_f32_16x16x32_bf16(a3, b0, acc[3][0], 0, 0, 0);
        acc[3][1] = __builtin_amdgcn_mfma_f32_16x16x32_bf16(a3, b1, acc[3][1], 0, 0, 0);
    }

    float bias0 = bias[n0 + wn * 32 + l16];
    float bias1 = bias[n0 + wn * 32 + 16 + l16];
    #pragma unroll
    for (int mt = 0; mt < 4; ++mt) {
        int mrow = m0 + wm * 64 + mt * 16 + quad * 4;
        #pragma unroll
        for (int nt = 0; nt < 2; ++nt) {
            int ncol = n0 + wn * 32 + nt * 16 + l16;
            float bv = nt ? bias1 : bias0;
            #pragma unroll
            for (int rg = 0; rg < 4; ++rg) {
                int m = mrow + rg;
                if (m < N_NODES)
                    out[(size_t)m * D_OUT + ncol] = acc[mt][nt][rg] + bv;
            }
        }
    }
}

extern "C" void kernel_launch(void* const* d_in, const int* in_sizes, int n_in,
                              void* d_out, int out_size, void* d_ws, size_t ws_size,
                              hipStream_t stream) {
    const float* x  = (const float*)d_in[0];
    const int*   ei = (const int*)d_in[1];
    const float* W  = (const float*)d_in[2];
    const float* b  = (const float*)d_in[3];
    float* out = (float*)d_out;

    char* ws = (char*)d_ws;
    __bf16* h    = (__bf16*)ws;
    int* cnt     = (int*)(ws + OFF_CNT);
    int* ovf_cnt = (int*)(ws + OFF_OVFC);
    int2* ovf    = (int2*)(ws + OFF_OVF);
    int* bucket  = (int*)(ws + OFF_BUCK);

    // zero cnt + ovf_cnt (contiguous region)
    hipMemsetAsync(cnt, 0, (OFF_OVFC - OFF_CNT) + 16, stream);

    k_bucket<<<(N_EDGES + 255) / 256, 256, 0, stream>>>(ei, cnt, bucket, ovf_cnt, ovf);
    k_agg<<<(N_NODES * 64 + 255) / 256, 256, 0, stream>>>(x, cnt, bucket, ovf_cnt, ovf, h);
    k_gemm<<<dim3(D_OUT / BN, (N_NODES + BM - 1) / BM), 256, 0, stream>>>(h, W, b, out);
}